// Round 4
// baseline (799.938 us; speedup 1.0000x reference)
//
#include <hip/hip_runtime.h>
#include <hip/hip_bf16.h>

typedef __bf16 bf16_t;
typedef __attribute__((ext_vector_type(8))) __bf16 bf16x8;
typedef __attribute__((ext_vector_type(4))) float f32x4;

// Direct HBM->LDS DMA, 16B per lane. LDS dest = wave-uniform base + lane*16.
#define GLOAD_LDS16(gp, lp)                                                    \
  __builtin_amdgcn_global_load_lds(                                            \
      (const __attribute__((address_space(1))) void*)(gp),                     \
      (__attribute__((address_space(3))) void*)(lp), 16, 0, 0)

// ---------------- prep kernels (tiny) ----------------
// Wvp[i][p] = sum_d Wv[i][d] * Wp[d][p]   (512 x 256)
// bvp[i]    = sum_d Wv[i][d] * bp[d] + bv[i]
__global__ void prep_wvp(const float* __restrict__ Wv, const float* __restrict__ Wp,
                         const float* __restrict__ bp, const float* __restrict__ bv,
                         float* __restrict__ Wvp, float* __restrict__ bvp) {
  const int i = blockIdx.x;
  const int j = threadIdx.x;
  float a = 0.f;
  for (int d = 0; d < 512; ++d) a += Wv[i * 512 + d] * Wp[d * 256 + j];
  Wvp[i * 256 + j] = a;
  if (j == 0) {
    float b = 0.f;
    for (int d = 0; d < 512; ++d) b += Wv[i * 512 + d] * bp[d];
    bvp[i] = b + bv[i];
  }
}

// Packed-B layout (all weight matrices, N x K row-major source):
//   element B[n][k] -> Bp[(((n>>4)*(K/32) + (k>>5))*64 + ((k>>3)&3)*16 + (n&15))*8 + (k&7)]
// i.e. for each 16-col group g and K-step t, 64 lanes x 16B contiguous (1 KB),
// exactly the per-wave MFMA B-fragment order: lane (q*16+r) holds B[16g+r][32t+8q..+7].
// A wave's fragment load is ONE fully-coalesced 1KB global_load_dwordx4 from L2.

// Wc packed: prep computes Wc[o][p] = sum_i Wo[o][i]*Wvp[i][p], writes packed (N=512,K=256)
__global__ void prep_wc(const float* __restrict__ Wo, const float* __restrict__ bo,
                        const float* __restrict__ Wvp, const float* __restrict__ bvp,
                        bf16_t* __restrict__ Wc, float* __restrict__ bcomb) {
  const int o = blockIdx.x;
  const int j = threadIdx.x;
  float a = 0.f;
  for (int i = 0; i < 512; ++i) a += Wo[o * 512 + i] * Wvp[i * 256 + j];
  const int g = o >> 4, rr = o & 15, t = j >> 5, q = (j >> 3) & 3, e = j & 7;
  Wc[((((size_t)g * 8 + t) * 64) + q * 16 + rr) * 8 + e] = (bf16_t)a;  // S=256/32=8
  if (j == 0) {
    float b = 0.f;
    for (int i = 0; i < 512; ++i) b += Wo[o * 512 + i] * bvp[i];
    bcomb[o] = b + bo[o];
  }
}

// cast W1 (N=1024,K=512) then W2 (N=512,K=1024) to bf16, packed layout
__global__ void prep_cast(const float* __restrict__ W1, const float* __restrict__ W2,
                          bf16_t* __restrict__ W1b, bf16_t* __restrict__ W2b) {
  const int idx = (blockIdx.x * 256 + threadIdx.x) * 8;
  const float* s;
  bf16_t* d;
  if (idx < 524288) {  // W1: K=512, S=16
    const int o = idx >> 9, k = idx & 511;
    const int g = o >> 4, rr = o & 15, t = k >> 5, q = (k >> 3) & 3;
    s = W1 + idx;
    d = W1b + ((((size_t)g * 16 + t) * 64) + q * 16 + rr) * 8;
  } else {             // W2: K=1024, S=32
    const int i2 = idx - 524288;
    const int o = i2 >> 10, k = i2 & 1023;
    const int g = o >> 4, rr = o & 15, t = k >> 5, q = (k >> 3) & 3;
    s = W2 + i2;
    d = W2b + ((((size_t)g * 32 + t) * 64) + q * 16 + rr) * 8;
  }
  float4 u0 = *(const float4*)s;
  float4 u1 = *(const float4*)(s + 4);
  bf16x8 v;
  v[0] = (bf16_t)u0.x; v[1] = (bf16_t)u0.y; v[2] = (bf16_t)u0.z; v[3] = (bf16_t)u0.w;
  v[4] = (bf16_t)u1.x; v[5] = (bf16_t)u1.y; v[6] = (bf16_t)u1.z; v[7] = (bf16_t)u1.w;
  *(bf16x8*)d = v;
}

// ---------------- fused GEMM ----------------
// C[m][n] = sum_k A[m][k] * Bw_packed[n][k]  (X @ W.T)
// Block tile: 128 rows x 512 cols, BK=32, 512 threads (8 waves, 2 row x 4 col grid).
// Wave (wr=w>>2, wc=w&3) owns rows [64wr,64wr+64) x cols [128wc,128wc+128):
// acc 4x8 frags of 16x16, 32 MFMA / K-step / wave.
//
// B path: NO LDS. Each B element is consumed by its owning wave only -> staged
// fragments straight from L2 (weights are 0.25-1MB, L2-resident) as 1KB coalesced
// loads in packed order. Ping-pong register prefetch (b0/b1) hides L2 latency
// under MFMA; B traffic is decoupled from the barrier.
//
// A path: swizzled-LDS double buffer (4x cross-wave reuse; fp32->bf16 convert for
// EPI0). 16-row windows of 1 KiB; slot s = r*4 + (q ^ ((r>>1)&3)) (round-2
// verified conflict-free). Staged via global_load_lds with pre-swizzled source.
//
// EPI 0: + bias + cell residual, LayerNorm(g,b) -> bf16 out (stride 512)
// EPI 1: + bias, exact GELU -> bf16 out (stride 1024)
// EPI 2: + bias + bf16 x residual, LayerNorm -> fp32 out (stride 512)
template <int K, int EPI>
__global__ __launch_bounds__(512, 2) void gemm_fused(
    const float* __restrict__ Af32, const bf16_t* __restrict__ Abf, const int lda,
    const bf16_t* __restrict__ Bw,
    const float* __restrict__ bias,
    const float* __restrict__ cellRes,
    const bf16_t* __restrict__ xRes,
    const float* __restrict__ gamma, const float* __restrict__ beta,
    bf16_t* __restrict__ outBf, float* __restrict__ outF32) {

  __shared__ __align__(16) bf16_t lA[2 * 128 * 32];  // 16 KiB (2 bufs x 8 windows)
  __shared__ float rs[4][128];
  __shared__ float rss[4][128];

  constexpr int S = K / 32;   // K-steps
  const int t = threadIdx.x;
  const int m0 = blockIdx.x * 128;
  const int n0 = blockIdx.y * 512;  // only nonzero for EPI==1 (N=1024)
  const int lane = t & 63;
  const int w = t >> 6;
  const int wr = w >> 2;      // row half 0..1
  const int wc = w & 3;       // col quarter 0..3
  const int r = lane & 15;
  const int q = lane >> 4;
  const int qs = q ^ ((r >> 1) & 3);

  // A LDS read base (bf16-element units) within wave's row range
  const int aRd = r * 32 + qs * 8;

  // A staging source mapping: lane l -> (row_in_window = l>>2, chunk = (l&3)^((l>>3)&3))
  const int srow = lane >> 2;
  const int sq = (lane & 3) ^ ((lane >> 3) & 3);

  // B packed base group for this wave
  const int g0 = (n0 >> 4) + 8 * wc;

  f32x4 acc[4][8];
#pragma unroll
  for (int i = 0; i < 4; ++i)
#pragma unroll
    for (int j = 0; j < 8; ++j)
#pragma unroll
      for (int p = 0; p < 4; ++p) acc[i][j][p] = 0.f;

  // EPI 0 A-staging: thread t -> row t>>2 (0..127), chunk t&3, swizzled slot.
  int aWr = 0;
  if constexpr (EPI == 0) {
    const int arow = t >> 2;
    const int c = t & 3;
    const int rr = arow & 15;
    aWr = (arow >> 4) * 512 + (rr * 4 + (c ^ ((rr >> 1) & 3))) * 8;
  }

  auto stageA = [&](int buf, int k0) {
    bf16_t* lAb = lA + (buf << 12);
    if constexpr (EPI == 0) {
      const float* src = Af32 + (size_t)(m0 + (t >> 2)) * lda + (k0 + (t & 3) * 8);
      float4 u0 = *(const float4*)src;
      float4 u1 = *(const float4*)(src + 4);
      bf16x8 v;
      v[0] = (bf16_t)u0.x; v[1] = (bf16_t)u0.y; v[2] = (bf16_t)u0.z; v[3] = (bf16_t)u0.w;
      v[4] = (bf16_t)u1.x; v[5] = (bf16_t)u1.y; v[6] = (bf16_t)u1.z; v[7] = (bf16_t)u1.w;
      *(bf16x8*)&lAb[aWr] = v;
    } else {
      const bf16_t* gp = Abf + (size_t)(m0 + 16 * w + srow) * lda + (k0 + sq * 8);
      GLOAD_LDS16(gp, &lAb[w * 512]);
    }
  };

  auto loadB = [&](bf16x8* dst, int step) {
#pragma unroll
    for (int j = 0; j < 8; ++j)
      dst[j] = *(const bf16x8*)(Bw + ((size_t)((g0 + j) * S + step) * 64 + lane) * 8);
  };

  auto compute = [&](int buf, const bf16x8* bq) {
    const bf16_t* lAb = lA + (buf << 12);
#pragma unroll
    for (int i = 0; i < 4; ++i) {
      const bf16x8 af = *(const bf16x8*)&lAb[(wr * 4 + i) * 512 + aRd];
#pragma unroll
      for (int j = 0; j < 8; ++j)
        acc[i][j] = __builtin_amdgcn_mfma_f32_16x16x32_bf16(af, bq[j], acc[i][j], 0, 0, 0);
    }
  };

  bf16x8 b0[8], b1[8];
  // prologue: step 0
  stageA(0, 0);
  loadB(b0, 0);
  __syncthreads();
  // ping-pong over pairs of K-steps (S is even for all instantiations)
  for (int s = 1; s < S; s += 2) {
    stageA(1, s * 32);
    loadB(b1, s);
    compute(0, b0);            // step s-1
    __syncthreads();           // buf1 resident; all reads of buf0 done
    if (s + 1 < S) {
      stageA(0, (s + 1) * 32);
      loadB(b0, s + 1);
    }
    compute(1, b1);            // step s
    if (s + 1 < S) __syncthreads();
  }

  if constexpr (EPI == 1) {
#pragma unroll
    for (int j = 0; j < 8; ++j) {
      const int colg = n0 + 128 * wc + 16 * j + r;
      const float bb = bias[colg];
#pragma unroll
      for (int i = 0; i < 4; ++i)
#pragma unroll
        for (int p = 0; p < 4; ++p) {
          const int rowg = m0 + 64 * wr + 16 * i + 4 * q + p;
          float v = acc[i][j][p] + bb;
          float g = 0.5f * v * (1.0f + erff(v * 0.70710678118654752f));
          outBf[(size_t)rowg * 1024 + colg] = (bf16_t)g;
        }
    }
  } else {
    float s_[4][4], ss[4][4];
#pragma unroll
    for (int i = 0; i < 4; ++i)
#pragma unroll
      for (int p = 0; p < 4; ++p) { s_[i][p] = 0.f; ss[i][p] = 0.f; }

#pragma unroll
    for (int j = 0; j < 8; ++j) {
      const int col = 128 * wc + 16 * j + r;
      const float bb = bias[col];
#pragma unroll
      for (int i = 0; i < 4; ++i)
#pragma unroll
        for (int p = 0; p < 4; ++p) {
          const int rowg = m0 + 64 * wr + 16 * i + 4 * q + p;
          float v = acc[i][j][p] + bb;
          if constexpr (EPI == 0) v += cellRes[(size_t)rowg * 512 + col];
          else                    v += (float)xRes[(size_t)rowg * 512 + col];
          acc[i][j][p] = v;
          s_[i][p] += v;
          ss[i][p] += v * v;
        }
    }
    // quad (16-lane) butterfly reduce over r
#pragma unroll
    for (int m = 1; m <= 8; m <<= 1) {
#pragma unroll
      for (int i = 0; i < 4; ++i)
#pragma unroll
        for (int p = 0; p < 4; ++p) {
          s_[i][p] += __shfl_xor(s_[i][p], m);
          ss[i][p] += __shfl_xor(ss[i][p], m);
        }
    }
    if (r == 0) {
#pragma unroll
      for (int i = 0; i < 4; ++i)
#pragma unroll
        for (int p = 0; p < 4; ++p) {
          const int rl = 64 * wr + 16 * i + 4 * q + p;
          rs[wc][rl] = s_[i][p];
          rss[wc][rl] = ss[i][p];
        }
    }
    __syncthreads();
    float mu[4][4], inv[4][4];
#pragma unroll
    for (int i = 0; i < 4; ++i)
#pragma unroll
      for (int p = 0; p < 4; ++p) {
        const int rl = 64 * wr + 16 * i + 4 * q + p;
        float tS = rs[0][rl] + rs[1][rl] + rs[2][rl] + rs[3][rl];
        float tQ = rss[0][rl] + rss[1][rl] + rss[2][rl] + rss[3][rl];
        float m_ = tS * (1.0f / 512.0f);
        float v_ = tQ * (1.0f / 512.0f) - m_ * m_;
        mu[i][p] = m_;
        inv[i][p] = rsqrtf(v_ + 1e-5f);
      }
#pragma unroll
    for (int j = 0; j < 8; ++j) {
      const int col = 128 * wc + 16 * j + r;
      const float ga = gamma[col], be = beta[col];
#pragma unroll
      for (int i = 0; i < 4; ++i)
#pragma unroll
        for (int p = 0; p < 4; ++p) {
          const int rowg = m0 + 64 * wr + 16 * i + 4 * q + p;
          float v = (acc[i][j][p] - mu[i][p]) * inv[i][p] * ga + be;
          if constexpr (EPI == 0) outBf[(size_t)rowg * 512 + col] = (bf16_t)v;
          else                    outF32[(size_t)rowg * 512 + col] = v;
        }
    }
  }
}

extern "C" void kernel_launch(void* const* d_in, const int* in_sizes, int n_in,
                              void* d_out, int out_size, void* d_ws, size_t ws_size,
                              hipStream_t stream) {
  const float* cell = (const float*)d_in[0];
  const float* pert = (const float*)d_in[1];
  const float* Wp   = (const float*)d_in[2];
  const float* bp   = (const float*)d_in[3];
  // d_in[4..7] = Wq,bq,Wk,bk: dead (softmax over a single key == 1 -> attn = v)
  const float* Wv   = (const float*)d_in[8];
  const float* bv   = (const float*)d_in[9];
  const float* Wo   = (const float*)d_in[10];
  const float* bo   = (const float*)d_in[11];
  const float* g1   = (const float*)d_in[12];
  const float* be1  = (const float*)d_in[13];
  const float* g2   = (const float*)d_in[14];
  const float* be2  = (const float*)d_in[15];
  const float* W1   = (const float*)d_in[16];
  const float* b1   = (const float*)d_in[17];
  const float* W2   = (const float*)d_in[18];
  const float* b2   = (const float*)d_in[19];

  char* ws = (char*)d_ws;
  float*  Wvp   = (float*)(ws + 0);          // 512*256*4   = 524288
  float*  bvp   = (float*)(ws + 524288);     // 512*4 (pad) = 2048
  float*  bcomb = (float*)(ws + 526336);     // 512*4 (pad) = 2048
  bf16_t* Wc    = (bf16_t*)(ws + 528384);    // 512*256*2   = 262144 (packed)
  bf16_t* W1b   = (bf16_t*)(ws + 790528);    // 1024*512*2  = 1048576 (packed)
  bf16_t* W2b   = (bf16_t*)(ws + 1839104);   // 512*1024*2  = 1048576 (packed)
  bf16_t* xws   = (bf16_t*)(ws + 2887680);   // 65536*512*2 = 67108864
  bf16_t* hws   = (bf16_t*)(ws + 69996544);  // 65536*1024*2 = 134217728
  (void)in_sizes; (void)n_in; (void)out_size; (void)ws_size;

  prep_wvp<<<512, 256, 0, stream>>>(Wv, Wp, bp, bv, Wvp, bvp);
  prep_wc<<<512, 256, 0, stream>>>(Wo, bo, Wvp, bvp, Wc, bcomb);
  prep_cast<<<512, 256, 0, stream>>>(W1, W2, W1b, W2b);

  // G1: attn (pert @ Wc.T + bcomb) + cell residual + LN1 -> x bf16
  gemm_fused<256, 0><<<dim3(512, 1), 512, 0, stream>>>(
      pert, nullptr, 256, Wc, bcomb, cell, nullptr, g1, be1, xws, nullptr);
  // G2: h = gelu(x @ W1.T + b1) -> bf16
  gemm_fused<512, 1><<<dim3(512, 2), 512, 0, stream>>>(
      nullptr, xws, 512, W1b, b1, nullptr, nullptr, nullptr, nullptr, hws, nullptr);
  // G3: out = LN2(x + h @ W2.T + b2) -> fp32
  gemm_fused<1024, 2><<<dim3(512, 1), 512, 0, stream>>>(
      nullptr, hws, 1024, W2b, b2, nullptr, xws, g2, be2, nullptr, (float*)d_out);
}

// Round 5
// 716.732 us; speedup vs baseline: 1.1161x; 1.1161x over previous
//
#include <hip/hip_runtime.h>
#include <hip/hip_bf16.h>

typedef __bf16 bf16_t;
typedef __attribute__((ext_vector_type(8))) __bf16 bf16x8;
typedef __attribute__((ext_vector_type(4))) float f32x4;

// Direct HBM->LDS DMA, 16B per lane. LDS dest = wave-uniform base + lane*16.
#define GLOAD_LDS16(gp, lp)                                                    \
  __builtin_amdgcn_global_load_lds(                                            \
      (const __attribute__((address_space(1))) void*)(gp),                     \
      (__attribute__((address_space(3))) void*)(lp), 16, 0, 0)

// ---------------- prep kernels (tiny) ----------------
__global__ void prep_wvp(const float* __restrict__ Wv, const float* __restrict__ Wp,
                         const float* __restrict__ bp, const float* __restrict__ bv,
                         float* __restrict__ Wvp, float* __restrict__ bvp) {
  const int i = blockIdx.x;
  const int j = threadIdx.x;
  float a = 0.f;
  for (int d = 0; d < 512; ++d) a += Wv[i * 512 + d] * Wp[d * 256 + j];
  Wvp[i * 256 + j] = a;
  if (j == 0) {
    float b = 0.f;
    for (int d = 0; d < 512; ++d) b += Wv[i * 512 + d] * bp[d];
    bvp[i] = b + bv[i];
  }
}

__global__ void prep_wc(const float* __restrict__ Wo, const float* __restrict__ bo,
                        const float* __restrict__ Wvp, const float* __restrict__ bvp,
                        bf16_t* __restrict__ Wc, float* __restrict__ bcomb) {
  const int o = blockIdx.x;
  const int j = threadIdx.x;
  float a = 0.f;
  for (int i = 0; i < 512; ++i) a += Wo[o * 512 + i] * Wvp[i * 256 + j];
  Wc[o * 256 + j] = (bf16_t)a;
  if (j == 0) {
    float b = 0.f;
    for (int i = 0; i < 512; ++i) b += Wo[o * 512 + i] * bvp[i];
    bcomb[o] = b + bo[o];
  }
}

// cast W1 (524288) then W2 (524288) to bf16 (row-major, same layout as source)
__global__ void prep_cast(const float* __restrict__ W1, const float* __restrict__ W2,
                          bf16_t* __restrict__ W1b, bf16_t* __restrict__ W2b) {
  const int idx = (blockIdx.x * 256 + threadIdx.x) * 8;
  const float* s;
  bf16_t* d;
  if (idx < 524288) { s = W1 + idx; d = W1b + idx; }
  else { s = W2 + (idx - 524288); d = W2b + (idx - 524288); }
  float4 u0 = *(const float4*)s;
  float4 u1 = *(const float4*)(s + 4);
  bf16x8 v;
  v[0] = (bf16_t)u0.x; v[1] = (bf16_t)u0.y; v[2] = (bf16_t)u0.z; v[3] = (bf16_t)u0.w;
  v[4] = (bf16_t)u1.x; v[5] = (bf16_t)u1.y; v[6] = (bf16_t)u1.z; v[7] = (bf16_t)u1.w;
  *(bf16x8*)d = v;
}

// ---------------- fused GEMM body ----------------
// C[m][n] = sum_k A[m][k] * Bw[n][k]  (Bw row-major N x K, i.e. X @ W.T)
// Block tile: 64 rows x 512 cols, BK=32, 256 threads (4 waves),
// wave w owns cols [128w, 128w+128), all 64 rows -> 4x8 tiles of 16x16.
//
// K-loop (EPI!=0): COUNTED-vmcnt pipeline (T3/T4):
//   per step: issue next tile's 9 DMAs -> s_waitcnt vmcnt(9) (waits only for
//   CURRENT tile; next tile's 9 stay in flight across the barrier and the
//   whole compute) -> s_barrier -> 4 phases of {2 B ds_reads, setprio(1),
//   8 MFMA, setprio(0)} -> s_barrier. vmcnt reaches 0 only on the last step.
//   Round-3's __syncthreads drained vmcnt(0) per step = serialized the full
//   36KB transfer against compute (m218: counted-vs-drain0 = +38-73%).
//
// LDS: 16-row windows of 1 KiB; 16B slot s = r*4 + (q ^ ((r>>1)&3)).
// Staged with pre-swizzled global source (linear lane->slot dest).
// ds_read_b128 conflict-free (round-2 verified: SQ_LDS_BANK_CONFLICT == 0).
//
// EPI 0: + bias + cell residual, LayerNorm(g,b) -> bf16 out (stride 512)
// EPI 1: + bias, exact GELU -> bf16 out (stride 1024)
// EPI 2: + bias + bf16 x residual, LayerNorm -> fp32 out (stride 512)
template <int K, int EPI>
__device__ __forceinline__ void gemm_body(
    const float* __restrict__ Af32, const bf16_t* __restrict__ Abf, const int lda,
    const bf16_t* __restrict__ Bw,
    const float* __restrict__ bias,
    const float* __restrict__ cellRes,
    const bf16_t* __restrict__ xRes,
    const float* __restrict__ gamma, const float* __restrict__ beta,
    bf16_t* __restrict__ outBf, float* __restrict__ outF32) {

  __shared__ __align__(16) bf16_t lA[2 * 64 * 32];    // 8 KiB
  __shared__ __align__(16) bf16_t lB[2 * 512 * 32];   // 64 KiB
  __shared__ float rs[4][64];
  __shared__ float rss[4][64];

  constexpr int S = K / 32;
  const int t = threadIdx.x;
  const int m0 = blockIdx.x * 64;
  const int n0 = blockIdx.y * 512;  // only nonzero for EPI==1 (N=1024)
  const int lane = t & 63;
  const int w = t >> 6;
  const int r = lane & 15;
  const int q = lane >> 4;
  const int qs = q ^ ((r >> 1) & 3);

  const int aRd = r * 32 + qs * 8;
  const int bRd = w * 4096 + r * 32 + qs * 8;

  const int srow = lane >> 2;
  const int sq = (lane & 3) ^ ((lane >> 3) & 3);

  f32x4 acc[4][8];
#pragma unroll
  for (int i = 0; i < 4; ++i)
#pragma unroll
    for (int j = 0; j < 8; ++j)
#pragma unroll
      for (int p = 0; p < 4; ++p) acc[i][j][p] = 0.f;

  int aWr = 0;
  if constexpr (EPI == 0) {
    const int arow = t >> 2;
    const int c = t & 3;
    const int rr = arow & 15;
    aWr = (arow >> 4) * 512 + (rr * 4 + (c ^ ((rr >> 1) & 3))) * 8;
  }

  auto stage = [&](int buf, int k0) {
    bf16_t* lBb = lB + (buf << 14);
    bf16_t* lAb = lA + (buf << 11);
#pragma unroll
    for (int i = 0; i < 8; ++i) {
      const bf16_t* gp = Bw + (size_t)(n0 + 64 * i + 16 * w + srow) * K + (k0 + sq * 8);
      GLOAD_LDS16(gp, &lBb[(i * 4 + w) * 512]);
    }
    if constexpr (EPI == 0) {
      const float* src = Af32 + (size_t)(m0 + (t >> 2)) * lda + (k0 + (t & 3) * 8);
      float4 u0 = *(const float4*)src;
      float4 u1 = *(const float4*)(src + 4);
      bf16x8 v;
      v[0] = (bf16_t)u0.x; v[1] = (bf16_t)u0.y; v[2] = (bf16_t)u0.z; v[3] = (bf16_t)u0.w;
      v[4] = (bf16_t)u1.x; v[5] = (bf16_t)u1.y; v[6] = (bf16_t)u1.z; v[7] = (bf16_t)u1.w;
      *(bf16x8*)&lAb[aWr] = v;
    } else {
      const bf16_t* gp = Abf + (size_t)(m0 + 16 * w + srow) * lda + (k0 + sq * 8);
      GLOAD_LDS16(gp, &lAb[w * 512]);
    }
  };

  // 4-phase compute: each phase reads 2 B frags then runs 8 MFMA under setprio.
  auto compute = [&](int buf) {
    const bf16_t* lAb = lA + (buf << 11);
    const bf16_t* lBb = lB + (buf << 14);
    bf16x8 af[4];
#pragma unroll
    for (int i = 0; i < 4; ++i) af[i] = *(const bf16x8*)&lAb[i * 512 + aRd];
#pragma unroll
    for (int ph = 0; ph < 4; ++ph) {
      bf16x8 b0 = *(const bf16x8*)&lBb[(2 * ph) * 512 + bRd];
      bf16x8 b1 = *(const bf16x8*)&lBb[(2 * ph + 1) * 512 + bRd];
      __builtin_amdgcn_s_setprio(1);
#pragma unroll
      for (int i = 0; i < 4; ++i) {
        acc[i][2 * ph] = __builtin_amdgcn_mfma_f32_16x16x32_bf16(af[i], b0, acc[i][2 * ph], 0, 0, 0);
        acc[i][2 * ph + 1] = __builtin_amdgcn_mfma_f32_16x16x32_bf16(af[i], b1, acc[i][2 * ph + 1], 0, 0, 0);
      }
      __builtin_amdgcn_s_setprio(0);
    }
  };

  if constexpr (EPI == 0) {
    // safe 2-phase loop (A path mixes reg loads + ds_write; K is short)
    stage(0, 0);
    __syncthreads();
    int cur = 0;
    for (int s = 1; s < S; ++s) {
      stage(cur ^ 1, s * 32);
      compute(cur);
      __syncthreads();
      cur ^= 1;
    }
    compute(cur);
  } else {
    // counted-vmcnt pipeline: loop VMEM = exactly 9 DMAs per step
    stage(0, 0);
    int cur = 0;
    for (int s = 0; s < S; ++s) {
      if (s + 1 < S) {
        stage(cur ^ 1, (s + 1) * 32);
        asm volatile("s_waitcnt vmcnt(9)" ::: "memory");  // current tile done; next in flight
      } else {
        asm volatile("s_waitcnt vmcnt(0)" ::: "memory");
      }
      __builtin_amdgcn_s_barrier();   // all waves: buf[cur] resident
      compute(cur);
      __builtin_amdgcn_s_barrier();   // all reads of buf[cur] done before overwrite
      cur ^= 1;
    }
  }

  if constexpr (EPI == 1) {
#pragma unroll
    for (int j = 0; j < 8; ++j) {
      const int colg = n0 + 128 * w + 16 * j + r;
      const float bb = bias[colg];
#pragma unroll
      for (int i = 0; i < 4; ++i)
#pragma unroll
        for (int p = 0; p < 4; ++p) {
          const int rowg = m0 + 16 * i + 4 * q + p;
          float v = acc[i][j][p] + bb;
          float g = 0.5f * v * (1.0f + erff(v * 0.70710678118654752f));
          outBf[(size_t)rowg * 1024 + colg] = (bf16_t)g;
        }
    }
  } else {
    float s_[4][4], ss[4][4];
#pragma unroll
    for (int i = 0; i < 4; ++i)
#pragma unroll
      for (int p = 0; p < 4; ++p) { s_[i][p] = 0.f; ss[i][p] = 0.f; }

#pragma unroll
    for (int j = 0; j < 8; ++j) {
      const int col = 128 * w + 16 * j + r;
      const float bb = bias[col];
#pragma unroll
      for (int i = 0; i < 4; ++i)
#pragma unroll
        for (int p = 0; p < 4; ++p) {
          const int rowg = m0 + 16 * i + 4 * q + p;
          float v = acc[i][j][p] + bb;
          if constexpr (EPI == 0) v += cellRes[(size_t)rowg * 512 + col];
          else                    v += (float)xRes[(size_t)rowg * 512 + col];
          acc[i][j][p] = v;
          s_[i][p] += v;
          ss[i][p] += v * v;
        }
    }
#pragma unroll
    for (int m = 1; m <= 8; m <<= 1) {
#pragma unroll
      for (int i = 0; i < 4; ++i)
#pragma unroll
        for (int p = 0; p < 4; ++p) {
          s_[i][p] += __shfl_xor(s_[i][p], m);
          ss[i][p] += __shfl_xor(ss[i][p], m);
        }
    }
    if (r == 0) {
#pragma unroll
      for (int i = 0; i < 4; ++i)
#pragma unroll
        for (int p = 0; p < 4; ++p) {
          rs[w][16 * i + 4 * q + p] = s_[i][p];
          rss[w][16 * i + 4 * q + p] = ss[i][p];
        }
    }
    __syncthreads();
    float mu[4][4], inv[4][4];
#pragma unroll
    for (int i = 0; i < 4; ++i)
#pragma unroll
      for (int p = 0; p < 4; ++p) {
        const int rl = 16 * i + 4 * q + p;
        float tS = rs[0][rl] + rs[1][rl] + rs[2][rl] + rs[3][rl];
        float tQ = rss[0][rl] + rss[1][rl] + rss[2][rl] + rss[3][rl];
        float m_ = tS * (1.0f / 512.0f);
        float v_ = tQ * (1.0f / 512.0f) - m_ * m_;
        mu[i][p] = m_;
        inv[i][p] = rsqrtf(v_ + 1e-5f);
      }
#pragma unroll
    for (int j = 0; j < 8; ++j) {
      const int col = 128 * w + 16 * j + r;
      const float ga = gamma[col], be = beta[col];
#pragma unroll
      for (int i = 0; i < 4; ++i)
#pragma unroll
        for (int p = 0; p < 4; ++p) {
          const int rowg = m0 + 16 * i + 4 * q + p;
          float v = (acc[i][j][p] - mu[i][p]) * inv[i][p] * ga + be;
          if constexpr (EPI == 0) outBf[(size_t)rowg * 512 + col] = (bf16_t)v;
          else                    outF32[(size_t)rowg * 512 + col] = v;
        }
    }
  }
}

// distinct names for per-stage rocprof attribution
__global__ __launch_bounds__(256, 2) void gemm_g1(
    const float* Af32, const bf16_t* Bw, const float* bias, const float* cellRes,
    const float* gamma, const float* beta, bf16_t* outBf) {
  gemm_body<256, 0>(Af32, nullptr, 256, Bw, bias, cellRes, nullptr, gamma, beta, outBf, nullptr);
}
__global__ __launch_bounds__(256, 2) void gemm_g2(
    const bf16_t* Abf, const bf16_t* Bw, const float* bias, bf16_t* outBf) {
  gemm_body<512, 1>(nullptr, Abf, 512, Bw, bias, nullptr, nullptr, nullptr, nullptr, outBf, nullptr);
}
__global__ __launch_bounds__(256, 2) void gemm_g3(
    const bf16_t* Abf, const bf16_t* Bw, const float* bias, const bf16_t* xRes,
    const float* gamma, const float* beta, float* outF32) {
  gemm_body<1024, 2>(nullptr, Abf, 1024, Bw, bias, nullptr, xRes, gamma, beta, nullptr, outF32);
}

extern "C" void kernel_launch(void* const* d_in, const int* in_sizes, int n_in,
                              void* d_out, int out_size, void* d_ws, size_t ws_size,
                              hipStream_t stream) {
  const float* cell = (const float*)d_in[0];
  const float* pert = (const float*)d_in[1];
  const float* Wp   = (const float*)d_in[2];
  const float* bp   = (const float*)d_in[3];
  // d_in[4..7] = Wq,bq,Wk,bk: dead (softmax over a single key == 1 -> attn = v)
  const float* Wv   = (const float*)d_in[8];
  const float* bv   = (const float*)d_in[9];
  const float* Wo   = (const float*)d_in[10];
  const float* bo   = (const float*)d_in[11];
  const float* g1   = (const float*)d_in[12];
  const float* be1  = (const float*)d_in[13];
  const float* g2   = (const float*)d_in[14];
  const float* be2  = (const float*)d_in[15];
  const float* W1   = (const float*)d_in[16];
  const float* b1   = (const float*)d_in[17];
  const float* W2   = (const float*)d_in[18];
  const float* b2   = (const float*)d_in[19];

  char* ws = (char*)d_ws;
  float*  Wvp   = (float*)(ws + 0);          // 512*256*4   = 524288
  float*  bvp   = (float*)(ws + 524288);     // 512*4 (pad) = 2048
  float*  bcomb = (float*)(ws + 526336);     // 512*4 (pad) = 2048
  bf16_t* Wc    = (bf16_t*)(ws + 528384);    // 512*256*2   = 262144
  bf16_t* W1b   = (bf16_t*)(ws + 790528);    // 1024*512*2  = 1048576
  bf16_t* W2b   = (bf16_t*)(ws + 1839104);   // 512*1024*2  = 1048576
  bf16_t* xws   = (bf16_t*)(ws + 2887680);   // 65536*512*2 = 67108864
  bf16_t* hws   = (bf16_t*)(ws + 69996544);  // 65536*1024*2 = 134217728
  (void)in_sizes; (void)n_in; (void)out_size; (void)ws_size;

  prep_wvp<<<512, 256, 0, stream>>>(Wv, Wp, bp, bv, Wvp, bvp);
  prep_wc<<<512, 256, 0, stream>>>(Wo, bo, Wvp, bvp, Wc, bcomb);
  prep_cast<<<512, 256, 0, stream>>>(W1, W2, W1b, W2b);

  // G1: attn (pert @ Wc.T + bcomb) + cell residual + LN1 -> x bf16
  gemm_g1<<<dim3(1024, 1), 256, 0, stream>>>(pert, Wc, bcomb, cell, g1, be1, xws);
  // G2: h = gelu(x @ W1.T + b1) -> bf16
  gemm_g2<<<dim3(1024, 2), 256, 0, stream>>>(xws, W1b, b1, hws);
  // G3: out = LN2(x + h @ W2.T + b2) -> fp32
  gemm_g3<<<dim3(1024, 1), 256, 0, stream>>>(hws, W2b, b2, xws, g2, be2, (float*)d_out);
}